// Round 18
// baseline (114.053 us; speedup 1.0000x reference)
//
#include <hip/hip_runtime.h>

typedef __attribute__((ext_vector_type(8))) short short8v;   // 8 bf16
typedef __attribute__((ext_vector_type(4))) short short4v;   // 4 bf16
typedef __attribute__((ext_vector_type(4))) float f32x4;

static __device__ __forceinline__ unsigned short f2bf(float f) {
  union { float f; unsigned u; } v;
  v.f = f;
  const unsigned u = v.u;
  return (unsigned short)((u + 0x7FFF + ((u >> 16) & 1)) >> 16);  // RNE
}
static __device__ __forceinline__ float bf2f(unsigned short s) {
  union { unsigned u; float f; } v;
  v.u = ((unsigned)s) << 16;
  return v.f;
}

// Intermediates xT,h1..h4 stored bf16 in [feature, B] layout (batch-last).

// ---------------- transpose x[B,784] f32 -> xT[784, Bc] bf16 ---------------
__global__ __launch_bounds__(256) void k_trb(const float* __restrict__ x,
                                             unsigned short* __restrict__ xT,
                                             int Bc) {
  __shared__ float t[32][33];
  const int b0 = blockIdx.x * 32;
  const int f0 = blockIdx.y * 32;
  const int tx = threadIdx.x, ty = threadIdx.y;
  for (int r = ty; r < 32; r += 8) {
    const int f = f0 + tx;
    t[r][tx] = (f < 784) ? x[(size_t)(b0 + r) * 784 + f] : 0.f;
  }
  __syncthreads();
  for (int r = ty; r < 32; r += 8) {
    const int f = f0 + r;
    if (f < 784) xT[(size_t)f * Bc + b0 + tx] = f2bf(t[tx][r]);
  }
}

// ------ LC weight -> bf16 [pos][o][Kpad], zero-padded k >= K ---------------
template <int O, int C, int NPOS, int Kpad>
__global__ void k_wmc(const float* __restrict__ w,
                      unsigned short* __restrict__ wm) {
  const int pos = blockIdx.x, o = blockIdx.y, k = threadIdx.x;
  float v = 0.f;
  if (k < C * 9) {
    const int c = k / 9, kk = k - c * 9;
    v = w[((size_t)(o * C + c) * NPOS + pos) * 9 + kk];
  }
  wm[((size_t)pos * O + o) * Kpad + k] = f2bf(v);
}

// ---------------- fw1 -> bf16 copy (once) ----------------------------------
__global__ __launch_bounds__(256) void k_wbf(const float* __restrict__ w,
                                             unsigned short* __restrict__ o) {
  const int i = (blockIdx.x * 256 + threadIdx.x) * 8;
  const float4 a = *(const float4*)&w[i];
  const float4 b = *(const float4*)&w[i + 4];
  short8v r;
  r[0] = (short)f2bf(a.x); r[1] = (short)f2bf(a.y);
  r[2] = (short)f2bf(a.z); r[3] = (short)f2bf(a.w);
  r[4] = (short)f2bf(b.x); r[5] = (short)f2bf(b.y);
  r[6] = (short)f2bf(b.z); r[7] = (short)f2bf(b.w);
  *(short8v*)&o[i] = r;
}

// ---------------- LC layer via bf16 MFMA (bf16 in, bf16 out) ---------------
// Flat 1-D grid with per-XCD btile-major swizzle: xcd = bid&7 walks its 8
// b-tiles position-major, so the X slab of the current b-tile stays L2-hot
// and is reused NPOS times (was: all 64 slabs touched sparsely -> L3-latency
// staging). Identity mapping when nbt % 8 != 0. KT=32 dbuf; rowtab gather
// (pad rows: load skipped, zeros packed); monotone-stagger Xl.
template <int O, int K, int NPOS, int HWIN, int WIN, int WOD, int STR,
          bool RELU>
__global__ __launch_bounds__(256) void k_lcm(
    const unsigned short* __restrict__ X, const unsigned short* __restrict__ Wm,
    const float* __restrict__ bias, unsigned short* __restrict__ out, int B) {
  constexpr int NSTEP = (K + 31) / 32;
  constexpr int Kpad = NSTEP * 32;
  constexpr int NBT = (O == 64) ? 8 : ((O == 32) ? 4 : 2);
  __shared__ short Wl[2][O * 40];
  __shared__ short Xl[2][5232];
  __shared__ int rowtab[Kpad];
  const int tid = threadIdx.x;
  // ---- grid swizzle: bid -> (btile, pos) ----
  const int nbt = B >> 7;  // b-tiles of 128
  int btile, pos;
  if ((nbt & 7) == 0) {
    const int xcd = blockIdx.x & 7, local = blockIdx.x >> 3;
    const int bl = local / NPOS;
    btile = xcd * (nbt >> 3) + bl;
    pos = local - bl * NPOS;
  } else {
    btile = blockIdx.x % nbt;
    pos = blockIdx.x / nbt;
  }
  const int b0 = btile * 128;
  const int ho = pos / WOD, wo = pos - ho * WOD;
  const int w = tid >> 6, l = tid & 63, m = l & 15, g = l >> 4;
  const int jw = (O == 64) ? w * 16 : ((O == 32) ? (w & 1) * 16 : 0);
  const int boff = (O == 64) ? 0 : ((O == 32) ? (w >> 1) * 64 : w * 32);

  for (int k = tid; k < Kpad; k += 256) {
    int r = 0;
    if (k < K) {
      const int c = k / 9, kk = k - c * 9;
      const int kh = kk / 3, kw = kk - kh * 3;
      r = c * HWIN + (ho * STR + kh) * WIN + (wo * STR + kw);
    }
    rowtab[k] = r;
  }
  __syncthreads();

  const unsigned short* wsrc = Wm + (size_t)pos * O * Kpad;
  const int wjj = tid >> 2, wko = (tid & 3) * 8;
  const bool wact = tid < O * 4;
  const int kp = tid >> 4, boct = (tid & 15) * 8;

  f32x4 acc[NBT];
#pragma unroll
  for (int bt = 0; bt < NBT; ++bt) acc[bt] = (f32x4){0.f, 0.f, 0.f, 0.f};

  short8v wreg, xa, xb;
  bool z0, z1;

  if (wact) wreg = *(const short8v*)&wsrc[(size_t)wjj * Kpad + wko];
  {
    const int k0 = 2 * kp;
    z0 = k0 >= K;
    z1 = k0 + 1 >= K;
    if (!z0) xa = *(const short8v*)(X + (size_t)rowtab[k0] * B + b0 + boct);
    if (!z1)
      xb = *(const short8v*)(X + (size_t)rowtab[k0 + 1] * B + b0 + boct);
  }
  if (wact) *(short8v*)&Wl[0][wjj * 40 + wko] = wreg;
  {
    unsigned* xl = (unsigned*)&Xl[0][0];
#pragma unroll
    for (int i = 0; i < 8; ++i) {
      const int b = boct + i;
      const unsigned lo = z0 ? 0u : (unsigned)(unsigned short)xa[i];
      const unsigned hi = z1 ? 0u : (unsigned)(unsigned short)xb[i];
      xl[b * 20 + (b >> 3) * 4 + kp] = lo | (hi << 16);
    }
  }
  __syncthreads();

  for (int t = 0; t < NSTEP; ++t) {
    const int cur = t & 1;
    if (t < NSTEP - 1) {
      const int kc = (t + 1) * 32;
      if (wact) wreg = *(const short8v*)&wsrc[(size_t)wjj * Kpad + kc + wko];
      const int k0 = kc + 2 * kp;
      z0 = k0 >= K;
      z1 = k0 + 1 >= K;
      if (!z0) xa = *(const short8v*)(X + (size_t)rowtab[k0] * B + b0 + boct);
      if (!z1)
        xb = *(const short8v*)(X + (size_t)rowtab[k0 + 1] * B + b0 + boct);
    }
    {
      const short8v aw = *(const short8v*)&Wl[cur][(jw + m) * 40 + g * 8];
      short8v bx[NBT];
#pragma unroll
      for (int bt = 0; bt < NBT; ++bt) {
        const int b = boff + bt * 16 + m;
        bx[bt] = *(const short8v*)&Xl[cur][b * 40 + (b >> 3) * 8 + g * 8];
      }
#pragma unroll
      for (int bt = 0; bt < NBT; ++bt)
        acc[bt] = __builtin_amdgcn_mfma_f32_16x16x32_bf16(aw, bx[bt], acc[bt],
                                                          0, 0, 0);
    }
    if (t < NSTEP - 1) {
      const int nxt = cur ^ 1;
      if (wact) *(short8v*)&Wl[nxt][wjj * 40 + wko] = wreg;
      unsigned* xl = (unsigned*)&Xl[nxt][0];
#pragma unroll
      for (int i = 0; i < 8; ++i) {
        const int b = boct + i;
        const unsigned lo = z0 ? 0u : (unsigned)(unsigned short)xa[i];
        const unsigned hi = z1 ? 0u : (unsigned)(unsigned short)xb[i];
        xl[b * 20 + (b >> 3) * 4 + kp] = lo | (hi << 16);
      }
    }
    __syncthreads();
  }

#pragma unroll
  for (int r = 0; r < 4; ++r) {
    const int o = jw + g * 4 + r;
    const int f = o * NPOS + pos;
    const float bz = bias[f];
#pragma unroll
    for (int bt = 0; bt < NBT; ++bt) {
      float v = acc[bt][r] + bz;
      if (RELU) v = fmaxf(v, 0.f);
      out[(size_t)f * B + b0 + boff + bt * 16 + m] = f2bf(v);
    }
  }
}

// ---------------- FC1 via bf16 MFMA, 64-b tiles (2 blocks/CU) --------------
__global__ __launch_bounds__(256) void k_fc1m(
    const unsigned short* __restrict__ X,
    const unsigned short* __restrict__ Wbf, const float* __restrict__ fb1,
    unsigned short* __restrict__ out, int B) {
  __shared__ short Wl[2][5120];   // 128 j x 40 shorts
  __shared__ short Xl[2][2608];   // 64 b x 40 + monotone stagger
  const int tid = threadIdx.x;
  const int b0 = blockIdx.x * 64, j0 = blockIdx.y * 128;
  const int w = tid >> 6, l = tid & 63, m = l & 15, g = l >> 4;

  const int wj = tid >> 1, wkh = (tid & 1) * 16;
  const unsigned short* wsrc = Wbf + (size_t)(j0 + wj) * 1024 + wkh;
  const int kp = tid >> 4, bq = (tid & 15) * 4;  // k-pair, 4 b per thread
  const unsigned short* xsrc = X + (size_t)(2 * kp) * B + b0 + bq;

  f32x4 acc[2][4];
#pragma unroll
  for (int jt = 0; jt < 2; ++jt)
#pragma unroll
    for (int bt = 0; bt < 4; ++bt) acc[jt][bt] = (f32x4){0.f, 0.f, 0.f, 0.f};

  short8v wreg0, wreg1;
  short4v xa, xb;

  wreg0 = *(const short8v*)(wsrc);
  wreg1 = *(const short8v*)(wsrc + 8);
  xa = *(const short4v*)(xsrc);
  xb = *(const short4v*)(xsrc + B);

  {
    *(short8v*)&Wl[0][wj * 40 + wkh] = wreg0;
    *(short8v*)&Wl[0][wj * 40 + wkh + 8] = wreg1;
    unsigned* xl = (unsigned*)&Xl[0][0];
#pragma unroll
    for (int i = 0; i < 4; ++i) {
      const int b = bq + i;
      xl[b * 20 + (b >> 3) * 4 + kp] = (unsigned)(unsigned short)xa[i] |
                                       ((unsigned)(unsigned short)xb[i] << 16);
    }
  }
  __syncthreads();

  for (int t = 0; t < 32; ++t) {
    const int cur = t & 1;
    if (t < 31) {
      const unsigned short* wp = wsrc + (t + 1) * 32;
      wreg0 = *(const short8v*)(wp);
      wreg1 = *(const short8v*)(wp + 8);
      const unsigned short* xp = xsrc + (size_t)(t + 1) * 32 * B;
      xa = *(const short4v*)(xp);
      xb = *(const short4v*)(xp + B);
    }
    {
      short8v aw[2], bx[4];
#pragma unroll
      for (int jt = 0; jt < 2; ++jt)
        aw[jt] = *(const short8v*)&Wl[cur][(w * 32 + jt * 16 + m) * 40 + g * 8];
#pragma unroll
      for (int bt = 0; bt < 4; ++bt) {
        const int b = bt * 16 + m;
        bx[bt] = *(const short8v*)&Xl[cur][b * 40 + (b >> 3) * 8 + g * 8];
      }
#pragma unroll
      for (int jt = 0; jt < 2; ++jt)
#pragma unroll
        for (int bt = 0; bt < 4; ++bt)
          acc[jt][bt] = __builtin_amdgcn_mfma_f32_16x16x32_bf16(
              aw[jt], bx[bt], acc[jt][bt], 0, 0, 0);
    }
    if (t < 31) {
      const int nxt = cur ^ 1;
      *(short8v*)&Wl[nxt][wj * 40 + wkh] = wreg0;
      *(short8v*)&Wl[nxt][wj * 40 + wkh + 8] = wreg1;
      unsigned* xl = (unsigned*)&Xl[nxt][0];
#pragma unroll
      for (int i = 0; i < 4; ++i) {
        const int b = bq + i;
        xl[b * 20 + (b >> 3) * 4 + kp] =
            (unsigned)(unsigned short)xa[i] |
            ((unsigned)(unsigned short)xb[i] << 16);
      }
    }
    __syncthreads();
  }

#pragma unroll
  for (int jt = 0; jt < 2; ++jt)
#pragma unroll
    for (int r = 0; r < 4; ++r) {
      const int j = j0 + w * 32 + jt * 16 + g * 4 + r;
      const float bj = fb1[j];
#pragma unroll
      for (int bt = 0; bt < 4; ++bt)
        out[(size_t)j * B + b0 + bt * 16 + m] =
            f2bf(fmaxf(acc[jt][bt][r] + bj, 0.f));
    }
}

// ---------------- FC2: out[b,10] = fw2[10,512] @ h4[512,B] + fb2 -----------
__global__ __launch_bounds__(512) void k_fc2(
    const unsigned short* __restrict__ in, const float* __restrict__ fw2,
    const float* __restrict__ fb2, float* __restrict__ out, int B, int b0) {
  __shared__ float red[8][10][64];
  const int tx = threadIdx.x;
  const int b = blockIdx.x * 64 + tx;
  const int tyu = threadIdx.y;
  float acc[10];
#pragma unroll
  for (int i = 0; i < 10; ++i) acc[i] = 0.f;
  for (int kk = 0; kk < 64; ++kk) {
    const int k = tyu * 64 + kk;
    const float v = bf2f(in[(size_t)k * B + b]);
#pragma unroll
    for (int i = 0; i < 10; ++i) acc[i] = fmaf(v, fw2[i * 512 + k], acc[i]);
  }
#pragma unroll
  for (int i = 0; i < 10; ++i) red[tyu][i][tx] = acc[i];
  __syncthreads();
  if (tyu == 0) {
#pragma unroll
    for (int i = 0; i < 10; ++i) {
      float s = fb2[i];
#pragma unroll
      for (int q = 0; q < 8; ++q) s += red[q][i][tx];
      out[(size_t)(b0 + b) * 10 + i] = s;
    }
  }
}

extern "C" void kernel_launch(void* const* d_in, const int* in_sizes, int n_in,
                              void* d_out, int out_size, void* d_ws,
                              size_t ws_size, hipStream_t stream) {
  const float* x   = (const float*)d_in[0];
  const float* w1  = (const float*)d_in[1];
  const float* b1  = (const float*)d_in[2];
  const float* w2  = (const float*)d_in[3];
  const float* b2  = (const float*)d_in[4];
  const float* w3  = (const float*)d_in[5];
  const float* b3  = (const float*)d_in[6];
  const float* fw1 = (const float*)d_in[7];
  const float* fb1 = (const float*)d_in[8];
  const float* fw2 = (const float*)d_in[9];
  const float* fb2 = (const float*)d_in[10];
  float* out = (float*)d_out;

  const int B = in_sizes[0] / 784;  // 8192

  // ws (float units): Wm1[169*16*32 bf16] | Wm2 | Wm3 | Wbf | bf16 buffers
  const size_t nWm1 = (size_t)169 * 16 * 32 / 2;
  const size_t nWm2 = (size_t)36 * 32 * 160 / 2;
  const size_t nWm3 = (size_t)16 * 64 * 288 / 2;
  const size_t nWbf = (size_t)512 * 1024 / 2;
  unsigned short* Wm1 = (unsigned short*)d_ws;
  unsigned short* Wm2 = (unsigned short*)((float*)d_ws + nWm1);
  unsigned short* Wm3 = (unsigned short*)((float*)d_ws + nWm1 + nWm2);
  unsigned short* Wbf = (unsigned short*)((float*)d_ws + nWm1 + nWm2 + nWm3);
  unsigned short* hbase =
      (unsigned short*)((float*)d_ws + nWm1 + nWm2 + nWm3 + nWbf);
  const size_t ws_rem =
      ws_size - (nWm1 + nWm2 + nWm3 + nWbf) * sizeof(float);

  // per-batch-element bf16 shorts: xT 784 + h1 2704 + h2 1152 + h3 1024 + h4 512
  const size_t per_elem = (size_t)(784 + 2704 + 1152 + 1024 + 512) * 2;
  int Bc = B;
  while ((size_t)Bc * per_elem > ws_rem && Bc > 512) Bc >>= 1;
  const int nch = B / Bc;

  unsigned short* XT = hbase;
  unsigned short* H1 = XT + (size_t)784 * Bc;
  unsigned short* H2 = H1 + (size_t)2704 * Bc;
  unsigned short* H3 = H2 + (size_t)1152 * Bc;
  unsigned short* H4 = H3 + (size_t)1024 * Bc;

  // one-time weight transforms
  k_wmc<16, 1, 169, 32><<<dim3(169, 16), 32, 0, stream>>>(w1, Wm1);
  k_wmc<32, 16, 36, 160><<<dim3(36, 32), 160, 0, stream>>>(w2, Wm2);
  k_wmc<64, 32, 16, 288><<<dim3(16, 64), 288, 0, stream>>>(w3, Wm3);
  k_wbf<<<dim3(256), 256, 0, stream>>>(fw1, Wbf);

  for (int ch = 0; ch < nch; ++ch) {
    const float* xc = x + (size_t)ch * Bc * 784;
    const int b0 = ch * Bc;
    const int nbt = Bc / 128;

    // transpose + bf16: x[B,784] -> xT[784,Bc]
    k_trb<<<dim3(Bc / 32, 25), dim3(32, 8), 0, stream>>>(xc, XT, Bc);
    // LC1 per-position MFMA GEMM, XCD-swizzled flat grid
    k_lcm<16, 9, 169, 784, 28, 13, 2, true>
        <<<dim3(nbt * 169), 256, 0, stream>>>(XT, Wm1, b1, H1, Bc);
    // LC2
    k_lcm<32, 144, 36, 169, 13, 6, 2, true>
        <<<dim3(nbt * 36), 256, 0, stream>>>(H1, Wm2, b2, H2, Bc);
    // LC3
    k_lcm<64, 288, 16, 36, 6, 4, 1, false>
        <<<dim3(nbt * 16), 256, 0, stream>>>(H2, Wm3, b3, H3, Bc);
    // FC1: h3 -> h4[512,Bc]  (64-b tiles: 512 blocks = 2/CU)
    k_fc1m<<<dim3(Bc / 64, 4), 256, 0, stream>>>(H3, Wbf, fb1, H4, Bc);
    // FC2: h4 -> out[b,10] f32  (8 waves/block)
    k_fc2<<<dim3(Bc / 64), dim3(64, 8), 0, stream>>>(H4, fw2, fb2, out, Bc,
                                                     b0);
  }
}

// Round 19
// 111.737 us; speedup vs baseline: 1.0207x; 1.0207x over previous
//
#include <hip/hip_runtime.h>

typedef __attribute__((ext_vector_type(8))) short short8v;   // 8 bf16
typedef __attribute__((ext_vector_type(4))) short short4v;   // 4 bf16
typedef __attribute__((ext_vector_type(4))) float f32x4;

static __device__ __forceinline__ unsigned short f2bf(float f) {
  union { float f; unsigned u; } v;
  v.f = f;
  const unsigned u = v.u;
  return (unsigned short)((u + 0x7FFF + ((u >> 16) & 1)) >> 16);  // RNE
}
static __device__ __forceinline__ float bf2f(unsigned short s) {
  union { unsigned u; float f; } v;
  v.u = ((unsigned)s) << 16;
  return v.f;
}

// Intermediates xT,h1..h4 stored bf16 in [feature, B] layout (batch-last).

// ---------------- transpose x[B,784] f32 -> xT[784, Bc] bf16 ---------------
__global__ __launch_bounds__(256) void k_trb(const float* __restrict__ x,
                                             unsigned short* __restrict__ xT,
                                             int Bc) {
  __shared__ float t[32][33];
  const int b0 = blockIdx.x * 32;
  const int f0 = blockIdx.y * 32;
  const int tx = threadIdx.x, ty = threadIdx.y;
  for (int r = ty; r < 32; r += 8) {
    const int f = f0 + tx;
    t[r][tx] = (f < 784) ? x[(size_t)(b0 + r) * 784 + f] : 0.f;
  }
  __syncthreads();
  for (int r = ty; r < 32; r += 8) {
    const int f = f0 + r;
    if (f < 784) xT[(size_t)f * Bc + b0 + tx] = f2bf(t[tx][r]);
  }
}

// ------ LC weight -> bf16 [pos][o][Kpad], zero-padded k >= K ---------------
template <int O, int C, int NPOS, int Kpad>
__global__ void k_wmc(const float* __restrict__ w,
                      unsigned short* __restrict__ wm) {
  const int pos = blockIdx.x, o = blockIdx.y, k = threadIdx.x;
  float v = 0.f;
  if (k < C * 9) {
    const int c = k / 9, kk = k - c * 9;
    v = w[((size_t)(o * C + c) * NPOS + pos) * 9 + kk];
  }
  wm[((size_t)pos * O + o) * Kpad + k] = f2bf(v);
}

// ---------------- fw1 -> bf16 copy (once) ----------------------------------
__global__ __launch_bounds__(256) void k_wbf(const float* __restrict__ w,
                                             unsigned short* __restrict__ o) {
  const int i = (blockIdx.x * 256 + threadIdx.x) * 8;
  const float4 a = *(const float4*)&w[i];
  const float4 b = *(const float4*)&w[i + 4];
  short8v r;
  r[0] = (short)f2bf(a.x); r[1] = (short)f2bf(a.y);
  r[2] = (short)f2bf(a.z); r[3] = (short)f2bf(a.w);
  r[4] = (short)f2bf(b.x); r[5] = (short)f2bf(b.y);
  r[6] = (short)f2bf(b.z); r[7] = (short)f2bf(b.w);
  *(short8v*)&o[i] = r;
}

// ---------------- LC layer via bf16 MFMA (bf16 in, bf16 out) ---------------
// Grid (btile, pos) 2D (R17 config — swizzle reverted, R18 showed neutral).
// KT=32 dbuf; rowtab gather (pad rows: load skipped, zeros packed);
// monotone-stagger Xl. Wave split minimizes ds_reads per MFMA:
//  O=64: wave = 32o x 64b  (2 jt x 4 bt -> 6 reads / 8 MFMA)
//  O=32: wave = 32o x 32b  (2 jt x 2 bt -> 4 reads / 4 MFMA)
//  O=16: wave = 16o x 32b  (1 jt x 2 bt -> 3 reads / 2 MFMA)
template <int O, int K, int NPOS, int HWIN, int WIN, int WOD, int STR,
          bool RELU>
__global__ __launch_bounds__(256) void k_lcm(
    const unsigned short* __restrict__ X, const unsigned short* __restrict__ Wm,
    const float* __restrict__ bias, unsigned short* __restrict__ out, int B) {
  constexpr int NSTEP = (K + 31) / 32;
  constexpr int Kpad = NSTEP * 32;
  constexpr int NJT = (O >= 32) ? 2 : 1;                      // o-tiles/wave
  constexpr int NBT = (O == 64) ? 4 : 2;                      // b-tiles/wave
  __shared__ short Wl[2][O * 40];
  __shared__ short Xl[2][5232];
  __shared__ int rowtab[Kpad];
  const int tid = threadIdx.x;
  const int b0 = blockIdx.x * 128;
  const int pos = blockIdx.y;
  const int ho = pos / WOD, wo = pos - ho * WOD;
  const int w = tid >> 6, l = tid & 63, m = l & 15, g = l >> 4;
  // wave tile origin
  const int jw = (O == 64) ? (w & 1) * 32 : 0;                // o origin
  const int boff = (O == 64) ? (w >> 1) * 64
                             : ((O == 32) ? w * 32 : (w & 3) * 32);

  for (int k = tid; k < Kpad; k += 256) {
    int r = 0;
    if (k < K) {
      const int c = k / 9, kk = k - c * 9;
      const int kh = kk / 3, kw = kk - kh * 3;
      r = c * HWIN + (ho * STR + kh) * WIN + (wo * STR + kw);
    }
    rowtab[k] = r;
  }
  __syncthreads();

  const unsigned short* wsrc = Wm + (size_t)pos * O * Kpad;
  const int wjj = tid >> 2, wko = (tid & 3) * 8;
  const bool wact = tid < O * 4;
  const int kp = tid >> 4, boct = (tid & 15) * 8;

  f32x4 acc[NJT][NBT];
#pragma unroll
  for (int jt = 0; jt < NJT; ++jt)
#pragma unroll
    for (int bt = 0; bt < NBT; ++bt) acc[jt][bt] = (f32x4){0.f, 0.f, 0.f, 0.f};

  short8v wreg, xa, xb;
  bool z0, z1;

  if (wact) wreg = *(const short8v*)&wsrc[(size_t)wjj * Kpad + wko];
  {
    const int k0 = 2 * kp;
    z0 = k0 >= K;
    z1 = k0 + 1 >= K;
    if (!z0) xa = *(const short8v*)(X + (size_t)rowtab[k0] * B + b0 + boct);
    if (!z1)
      xb = *(const short8v*)(X + (size_t)rowtab[k0 + 1] * B + b0 + boct);
  }
  if (wact) *(short8v*)&Wl[0][wjj * 40 + wko] = wreg;
  {
    unsigned* xl = (unsigned*)&Xl[0][0];
#pragma unroll
    for (int i = 0; i < 8; ++i) {
      const int b = boct + i;
      const unsigned lo = z0 ? 0u : (unsigned)(unsigned short)xa[i];
      const unsigned hi = z1 ? 0u : (unsigned)(unsigned short)xb[i];
      xl[b * 20 + (b >> 3) * 4 + kp] = lo | (hi << 16);
    }
  }
  __syncthreads();

  for (int t = 0; t < NSTEP; ++t) {
    const int cur = t & 1;
    if (t < NSTEP - 1) {
      const int kc = (t + 1) * 32;
      if (wact) wreg = *(const short8v*)&wsrc[(size_t)wjj * Kpad + kc + wko];
      const int k0 = kc + 2 * kp;
      z0 = k0 >= K;
      z1 = k0 + 1 >= K;
      if (!z0) xa = *(const short8v*)(X + (size_t)rowtab[k0] * B + b0 + boct);
      if (!z1)
        xb = *(const short8v*)(X + (size_t)rowtab[k0 + 1] * B + b0 + boct);
    }
    {
      short8v aw[NJT], bx[NBT];
#pragma unroll
      for (int jt = 0; jt < NJT; ++jt)
        aw[jt] = *(const short8v*)&Wl[cur][(jw + jt * 16 + m) * 40 + g * 8];
#pragma unroll
      for (int bt = 0; bt < NBT; ++bt) {
        const int b = boff + bt * 16 + m;
        bx[bt] = *(const short8v*)&Xl[cur][b * 40 + (b >> 3) * 8 + g * 8];
      }
#pragma unroll
      for (int jt = 0; jt < NJT; ++jt)
#pragma unroll
        for (int bt = 0; bt < NBT; ++bt)
          acc[jt][bt] = __builtin_amdgcn_mfma_f32_16x16x32_bf16(
              aw[jt], bx[bt], acc[jt][bt], 0, 0, 0);
    }
    if (t < NSTEP - 1) {
      const int nxt = cur ^ 1;
      if (wact) *(short8v*)&Wl[nxt][wjj * 40 + wko] = wreg;
      unsigned* xl = (unsigned*)&Xl[nxt][0];
#pragma unroll
      for (int i = 0; i < 8; ++i) {
        const int b = boct + i;
        const unsigned lo = z0 ? 0u : (unsigned)(unsigned short)xa[i];
        const unsigned hi = z1 ? 0u : (unsigned)(unsigned short)xb[i];
        xl[b * 20 + (b >> 3) * 4 + kp] = lo | (hi << 16);
      }
    }
    __syncthreads();
  }

#pragma unroll
  for (int jt = 0; jt < NJT; ++jt)
#pragma unroll
    for (int r = 0; r < 4; ++r) {
      const int o = jw + jt * 16 + g * 4 + r;
      const int f = o * NPOS + pos;
      const float bz = bias[f];
#pragma unroll
      for (int bt = 0; bt < NBT; ++bt) {
        float v = acc[jt][bt][r] + bz;
        if (RELU) v = fmaxf(v, 0.f);
        out[(size_t)f * B + b0 + boff + bt * 16 + m] = f2bf(v);
      }
    }
}

// ---------------- FC1 via bf16 MFMA, 64-b tiles (2 blocks/CU) --------------
__global__ __launch_bounds__(256) void k_fc1m(
    const unsigned short* __restrict__ X,
    const unsigned short* __restrict__ Wbf, const float* __restrict__ fb1,
    unsigned short* __restrict__ out, int B) {
  __shared__ short Wl[2][5120];   // 128 j x 40 shorts
  __shared__ short Xl[2][2608];   // 64 b x 40 + monotone stagger
  const int tid = threadIdx.x;
  const int b0 = blockIdx.x * 64, j0 = blockIdx.y * 128;
  const int w = tid >> 6, l = tid & 63, m = l & 15, g = l >> 4;

  const int wj = tid >> 1, wkh = (tid & 1) * 16;
  const unsigned short* wsrc = Wbf + (size_t)(j0 + wj) * 1024 + wkh;
  const int kp = tid >> 4, bq = (tid & 15) * 4;  // k-pair, 4 b per thread
  const unsigned short* xsrc = X + (size_t)(2 * kp) * B + b0 + bq;

  f32x4 acc[2][4];
#pragma unroll
  for (int jt = 0; jt < 2; ++jt)
#pragma unroll
    for (int bt = 0; bt < 4; ++bt) acc[jt][bt] = (f32x4){0.f, 0.f, 0.f, 0.f};

  short8v wreg0, wreg1;
  short4v xa, xb;

  wreg0 = *(const short8v*)(wsrc);
  wreg1 = *(const short8v*)(wsrc + 8);
  xa = *(const short4v*)(xsrc);
  xb = *(const short4v*)(xsrc + B);

  {
    *(short8v*)&Wl[0][wj * 40 + wkh] = wreg0;
    *(short8v*)&Wl[0][wj * 40 + wkh + 8] = wreg1;
    unsigned* xl = (unsigned*)&Xl[0][0];
#pragma unroll
    for (int i = 0; i < 4; ++i) {
      const int b = bq + i;
      xl[b * 20 + (b >> 3) * 4 + kp] = (unsigned)(unsigned short)xa[i] |
                                       ((unsigned)(unsigned short)xb[i] << 16);
    }
  }
  __syncthreads();

  for (int t = 0; t < 32; ++t) {
    const int cur = t & 1;
    if (t < 31) {
      const unsigned short* wp = wsrc + (t + 1) * 32;
      wreg0 = *(const short8v*)(wp);
      wreg1 = *(const short8v*)(wp + 8);
      const unsigned short* xp = xsrc + (size_t)(t + 1) * 32 * B;
      xa = *(const short4v*)(xp);
      xb = *(const short4v*)(xp + B);
    }
    {
      short8v aw[2], bx[4];
#pragma unroll
      for (int jt = 0; jt < 2; ++jt)
        aw[jt] = *(const short8v*)&Wl[cur][(w * 32 + jt * 16 + m) * 40 + g * 8];
#pragma unroll
      for (int bt = 0; bt < 4; ++bt) {
        const int b = bt * 16 + m;
        bx[bt] = *(const short8v*)&Xl[cur][b * 40 + (b >> 3) * 8 + g * 8];
      }
#pragma unroll
      for (int jt = 0; jt < 2; ++jt)
#pragma unroll
        for (int bt = 0; bt < 4; ++bt)
          acc[jt][bt] = __builtin_amdgcn_mfma_f32_16x16x32_bf16(
              aw[jt], bx[bt], acc[jt][bt], 0, 0, 0);
    }
    if (t < 31) {
      const int nxt = cur ^ 1;
      *(short8v*)&Wl[nxt][wj * 40 + wkh] = wreg0;
      *(short8v*)&Wl[nxt][wj * 40 + wkh + 8] = wreg1;
      unsigned* xl = (unsigned*)&Xl[nxt][0];
#pragma unroll
      for (int i = 0; i < 4; ++i) {
        const int b = bq + i;
        xl[b * 20 + (b >> 3) * 4 + kp] =
            (unsigned)(unsigned short)xa[i] |
            ((unsigned)(unsigned short)xb[i] << 16);
      }
    }
    __syncthreads();
  }

#pragma unroll
  for (int jt = 0; jt < 2; ++jt)
#pragma unroll
    for (int r = 0; r < 4; ++r) {
      const int j = j0 + w * 32 + jt * 16 + g * 4 + r;
      const float bj = fb1[j];
#pragma unroll
      for (int bt = 0; bt < 4; ++bt)
        out[(size_t)j * B + b0 + bt * 16 + m] =
            f2bf(fmaxf(acc[jt][bt][r] + bj, 0.f));
    }
}

// ---------------- FC2: out[b,10] = fw2[10,512] @ h4[512,B] + fb2 -----------
__global__ __launch_bounds__(512) void k_fc2(
    const unsigned short* __restrict__ in, const float* __restrict__ fw2,
    const float* __restrict__ fb2, float* __restrict__ out, int B, int b0) {
  __shared__ float red[8][10][64];
  const int tx = threadIdx.x;
  const int b = blockIdx.x * 64 + tx;
  const int tyu = threadIdx.y;
  float acc[10];
#pragma unroll
  for (int i = 0; i < 10; ++i) acc[i] = 0.f;
  for (int kk = 0; kk < 64; ++kk) {
    const int k = tyu * 64 + kk;
    const float v = bf2f(in[(size_t)k * B + b]);
#pragma unroll
    for (int i = 0; i < 10; ++i) acc[i] = fmaf(v, fw2[i * 512 + k], acc[i]);
  }
#pragma unroll
  for (int i = 0; i < 10; ++i) red[tyu][i][tx] = acc[i];
  __syncthreads();
  if (tyu == 0) {
#pragma unroll
    for (int i = 0; i < 10; ++i) {
      float s = fb2[i];
#pragma unroll
      for (int q = 0; q < 8; ++q) s += red[q][i][tx];
      out[(size_t)(b0 + b) * 10 + i] = s;
    }
  }
}

extern "C" void kernel_launch(void* const* d_in, const int* in_sizes, int n_in,
                              void* d_out, int out_size, void* d_ws,
                              size_t ws_size, hipStream_t stream) {
  const float* x   = (const float*)d_in[0];
  const float* w1  = (const float*)d_in[1];
  const float* b1  = (const float*)d_in[2];
  const float* w2  = (const float*)d_in[3];
  const float* b2  = (const float*)d_in[4];
  const float* w3  = (const float*)d_in[5];
  const float* b3  = (const float*)d_in[6];
  const float* fw1 = (const float*)d_in[7];
  const float* fb1 = (const float*)d_in[8];
  const float* fw2 = (const float*)d_in[9];
  const float* fb2 = (const float*)d_in[10];
  float* out = (float*)d_out;

  const int B = in_sizes[0] / 784;  // 8192

  // ws (float units): Wm1[169*16*32 bf16] | Wm2 | Wm3 | Wbf | bf16 buffers
  const size_t nWm1 = (size_t)169 * 16 * 32 / 2;
  const size_t nWm2 = (size_t)36 * 32 * 160 / 2;
  const size_t nWm3 = (size_t)16 * 64 * 288 / 2;
  const size_t nWbf = (size_t)512 * 1024 / 2;
  unsigned short* Wm1 = (unsigned short*)d_ws;
  unsigned short* Wm2 = (unsigned short*)((float*)d_ws + nWm1);
  unsigned short* Wm3 = (unsigned short*)((float*)d_ws + nWm1 + nWm2);
  unsigned short* Wbf = (unsigned short*)((float*)d_ws + nWm1 + nWm2 + nWm3);
  unsigned short* hbase =
      (unsigned short*)((float*)d_ws + nWm1 + nWm2 + nWm3 + nWbf);
  const size_t ws_rem =
      ws_size - (nWm1 + nWm2 + nWm3 + nWbf) * sizeof(float);

  // per-batch-element bf16 shorts: xT 784 + h1 2704 + h2 1152 + h3 1024 + h4 512
  const size_t per_elem = (size_t)(784 + 2704 + 1152 + 1024 + 512) * 2;
  int Bc = B;
  while ((size_t)Bc * per_elem > ws_rem && Bc > 512) Bc >>= 1;
  const int nch = B / Bc;

  unsigned short* XT = hbase;
  unsigned short* H1 = XT + (size_t)784 * Bc;
  unsigned short* H2 = H1 + (size_t)2704 * Bc;
  unsigned short* H3 = H2 + (size_t)1152 * Bc;
  unsigned short* H4 = H3 + (size_t)1024 * Bc;

  // one-time weight transforms
  k_wmc<16, 1, 169, 32><<<dim3(169, 16), 32, 0, stream>>>(w1, Wm1);
  k_wmc<32, 16, 36, 160><<<dim3(36, 32), 160, 0, stream>>>(w2, Wm2);
  k_wmc<64, 32, 16, 288><<<dim3(16, 64), 288, 0, stream>>>(w3, Wm3);
  k_wbf<<<dim3(256), 256, 0, stream>>>(fw1, Wbf);

  for (int ch = 0; ch < nch; ++ch) {
    const float* xc = x + (size_t)ch * Bc * 784;
    const int b0 = ch * Bc;
    const int nbt = Bc / 128;

    // transpose + bf16: x[B,784] -> xT[784,Bc]
    k_trb<<<dim3(Bc / 32, 25), dim3(32, 8), 0, stream>>>(xc, XT, Bc);
    // LC1 per-position MFMA GEMM
    k_lcm<16, 9, 169, 784, 28, 13, 2, true>
        <<<dim3(nbt, 169), 256, 0, stream>>>(XT, Wm1, b1, H1, Bc);
    // LC2
    k_lcm<32, 144, 36, 169, 13, 6, 2, true>
        <<<dim3(nbt, 36), 256, 0, stream>>>(H1, Wm2, b2, H2, Bc);
    // LC3
    k_lcm<64, 288, 16, 36, 6, 4, 1, false>
        <<<dim3(nbt, 16), 256, 0, stream>>>(H2, Wm3, b3, H3, Bc);
    // FC1: h3 -> h4[512,Bc]  (64-b tiles: 512 blocks = 2/CU)
    k_fc1m<<<dim3(Bc / 64, 4), 256, 0, stream>>>(H3, Wbf, fb1, H4, Bc);
    // FC2: h4 -> out[b,10] f32  (8 waves/block)
    k_fc2<<<dim3(Bc / 64), dim3(64, 8), 0, stream>>>(H4, fw2, fb2, out, Bc,
                                                     b0);
  }
}

// Round 20
// 109.299 us; speedup vs baseline: 1.0435x; 1.0223x over previous
//
#include <hip/hip_runtime.h>

typedef __attribute__((ext_vector_type(8))) short short8v;   // 8 bf16
typedef __attribute__((ext_vector_type(4))) short short4v;   // 4 bf16
typedef __attribute__((ext_vector_type(4))) float f32x4;

static __device__ __forceinline__ unsigned short f2bf(float f) {
  union { float f; unsigned u; } v;
  v.f = f;
  const unsigned u = v.u;
  return (unsigned short)((u + 0x7FFF + ((u >> 16) & 1)) >> 16);  // RNE
}
static __device__ __forceinline__ float bf2f(unsigned short s) {
  union { unsigned u; float f; } v;
  v.u = ((unsigned)s) << 16;
  return v.f;
}

// Intermediates xT,h1..h4 stored bf16 in [feature, B] layout (batch-last).

// ---------------- transpose x[B,784] f32 -> xT[784, Bc] bf16 ---------------
__global__ __launch_bounds__(256) void k_trb(const float* __restrict__ x,
                                             unsigned short* __restrict__ xT,
                                             int Bc) {
  __shared__ float t[32][33];
  const int b0 = blockIdx.x * 32;
  const int f0 = blockIdx.y * 32;
  const int tx = threadIdx.x, ty = threadIdx.y;
  for (int r = ty; r < 32; r += 8) {
    const int f = f0 + tx;
    t[r][tx] = (f < 784) ? x[(size_t)(b0 + r) * 784 + f] : 0.f;
  }
  __syncthreads();
  for (int r = ty; r < 32; r += 8) {
    const int f = f0 + r;
    if (f < 784) xT[(size_t)f * Bc + b0 + tx] = f2bf(t[tx][r]);
  }
}

// ------ LC weight -> bf16 [pos][o][Kpad], zero-padded k >= K ---------------
template <int O, int C, int NPOS, int Kpad>
__global__ void k_wmc(const float* __restrict__ w,
                      unsigned short* __restrict__ wm) {
  const int pos = blockIdx.x, o = blockIdx.y, k = threadIdx.x;
  float v = 0.f;
  if (k < C * 9) {
    const int c = k / 9, kk = k - c * 9;
    v = w[((size_t)(o * C + c) * NPOS + pos) * 9 + kk];
  }
  wm[((size_t)pos * O + o) * Kpad + k] = f2bf(v);
}

// ---------------- fw1 -> bf16 copy (once) ----------------------------------
__global__ __launch_bounds__(256) void k_wbf(const float* __restrict__ w,
                                             unsigned short* __restrict__ o) {
  const int i = (blockIdx.x * 256 + threadIdx.x) * 8;
  const float4 a = *(const float4*)&w[i];
  const float4 b = *(const float4*)&w[i + 4];
  short8v r;
  r[0] = (short)f2bf(a.x); r[1] = (short)f2bf(a.y);
  r[2] = (short)f2bf(a.z); r[3] = (short)f2bf(a.w);
  r[4] = (short)f2bf(b.x); r[5] = (short)f2bf(b.y);
  r[6] = (short)f2bf(b.z); r[7] = (short)f2bf(b.w);
  *(short8v*)&o[i] = r;
}

// ---------------- LC layer via bf16 MFMA (bf16 in, bf16 out) ---------------
// SINGLE-buffered LDS (R20): halves LDS/block -> all three LC layers hit the
// 8-blocks/CU TLP cap (was 4-6, LDS-capped by the double buffer). Register
// prefetch of the next K-step's X rows still hides global latency across the
// two per-step barriers; cross-block TLP covers the rest (m114).
// Wave split: O=64: 32o x 64b (2jt x 4bt); O=32: 32o x 32b; O=16: 16o x 32b.
template <int O, int K, int NPOS, int HWIN, int WIN, int WOD, int STR,
          bool RELU>
__global__ __launch_bounds__(256) void k_lcm(
    const unsigned short* __restrict__ X, const unsigned short* __restrict__ Wm,
    const float* __restrict__ bias, unsigned short* __restrict__ out, int B) {
  constexpr int NSTEP = (K + 31) / 32;
  constexpr int Kpad = NSTEP * 32;
  constexpr int NJT = (O >= 32) ? 2 : 1;                      // o-tiles/wave
  constexpr int NBT = (O == 64) ? 4 : 2;                      // b-tiles/wave
  __shared__ short Wl[O * 40];
  __shared__ short Xl[5232];
  __shared__ int rowtab[Kpad];
  const int tid = threadIdx.x;
  const int b0 = blockIdx.x * 128;
  const int pos = blockIdx.y;
  const int ho = pos / WOD, wo = pos - ho * WOD;
  const int w = tid >> 6, l = tid & 63, m = l & 15, g = l >> 4;
  const int jw = (O == 64) ? (w & 1) * 32 : 0;                // o origin
  const int boff = (O == 64) ? (w >> 1) * 64
                             : ((O == 32) ? w * 32 : (w & 3) * 32);

  for (int k = tid; k < Kpad; k += 256) {
    int r = 0;
    if (k < K) {
      const int c = k / 9, kk = k - c * 9;
      const int kh = kk / 3, kw = kk - kh * 3;
      r = c * HWIN + (ho * STR + kh) * WIN + (wo * STR + kw);
    }
    rowtab[k] = r;
  }
  __syncthreads();

  const unsigned short* wsrc = Wm + (size_t)pos * O * Kpad;
  const int wjj = tid >> 2, wko = (tid & 3) * 8;
  const bool wact = tid < O * 4;
  const int kp = tid >> 4, boct = (tid & 15) * 8;

  f32x4 acc[NJT][NBT];
#pragma unroll
  for (int jt = 0; jt < NJT; ++jt)
#pragma unroll
    for (int bt = 0; bt < NBT; ++bt) acc[jt][bt] = (f32x4){0.f, 0.f, 0.f, 0.f};

  short8v wreg, xa, xb;
  bool z0, z1;

  // ---- prologue: load + stage step 0
  if (wact) wreg = *(const short8v*)&wsrc[(size_t)wjj * Kpad + wko];
  {
    const int k0 = 2 * kp;
    z0 = k0 >= K;
    z1 = k0 + 1 >= K;
    if (!z0) xa = *(const short8v*)(X + (size_t)rowtab[k0] * B + b0 + boct);
    if (!z1)
      xb = *(const short8v*)(X + (size_t)rowtab[k0 + 1] * B + b0 + boct);
  }
  if (wact) *(short8v*)&Wl[wjj * 40 + wko] = wreg;
  {
    unsigned* xl = (unsigned*)&Xl[0];
#pragma unroll
    for (int i = 0; i < 8; ++i) {
      const int b = boct + i;
      const unsigned lo = z0 ? 0u : (unsigned)(unsigned short)xa[i];
      const unsigned hi = z1 ? 0u : (unsigned)(unsigned short)xb[i];
      xl[b * 20 + (b >> 3) * 4 + kp] = lo | (hi << 16);
    }
  }
  __syncthreads();

  for (int t = 0; t < NSTEP; ++t) {
    if (t < NSTEP - 1) {  // issue next step's loads into registers
      const int kc = (t + 1) * 32;
      if (wact) wreg = *(const short8v*)&wsrc[(size_t)wjj * Kpad + kc + wko];
      const int k0 = kc + 2 * kp;
      z0 = k0 >= K;
      z1 = k0 + 1 >= K;
      if (!z0) xa = *(const short8v*)(X + (size_t)rowtab[k0] * B + b0 + boct);
      if (!z1)
        xb = *(const short8v*)(X + (size_t)rowtab[k0 + 1] * B + b0 + boct);
    }
    {
      short8v aw[NJT], bx[NBT];
#pragma unroll
      for (int jt = 0; jt < NJT; ++jt)
        aw[jt] = *(const short8v*)&Wl[(jw + jt * 16 + m) * 40 + g * 8];
#pragma unroll
      for (int bt = 0; bt < NBT; ++bt) {
        const int b = boff + bt * 16 + m;
        bx[bt] = *(const short8v*)&Xl[b * 40 + (b >> 3) * 8 + g * 8];
      }
#pragma unroll
      for (int jt = 0; jt < NJT; ++jt)
#pragma unroll
        for (int bt = 0; bt < NBT; ++bt)
          acc[jt][bt] = __builtin_amdgcn_mfma_f32_16x16x32_bf16(
              aw[jt], bx[bt], acc[jt][bt], 0, 0, 0);
    }
    if (t < NSTEP - 1) {
      __syncthreads();  // all waves done reading Xl/Wl
      if (wact) *(short8v*)&Wl[wjj * 40 + wko] = wreg;
      unsigned* xl = (unsigned*)&Xl[0];
#pragma unroll
      for (int i = 0; i < 8; ++i) {
        const int b = boct + i;
        const unsigned lo = z0 ? 0u : (unsigned)(unsigned short)xa[i];
        const unsigned hi = z1 ? 0u : (unsigned)(unsigned short)xb[i];
        xl[b * 20 + (b >> 3) * 4 + kp] = lo | (hi << 16);
      }
      __syncthreads();  // writes visible before next MFMA
    }
  }

#pragma unroll
  for (int jt = 0; jt < NJT; ++jt)
#pragma unroll
    for (int r = 0; r < 4; ++r) {
      const int o = jw + jt * 16 + g * 4 + r;
      const int f = o * NPOS + pos;
      const float bz = bias[f];
#pragma unroll
      for (int bt = 0; bt < NBT; ++bt) {
        float v = acc[jt][bt][r] + bz;
        if (RELU) v = fmaxf(v, 0.f);
        out[(size_t)f * B + b0 + boff + bt * 16 + m] = f2bf(v);
      }
    }
}

// ---------------- FC1 via bf16 MFMA, 64-b tiles (2 blocks/CU) --------------
// Grid-capped at 2 blocks/CU (512 blocks), so double-buffer stays.
__global__ __launch_bounds__(256) void k_fc1m(
    const unsigned short* __restrict__ X,
    const unsigned short* __restrict__ Wbf, const float* __restrict__ fb1,
    unsigned short* __restrict__ out, int B) {
  __shared__ short Wl[2][5120];   // 128 j x 40 shorts
  __shared__ short Xl[2][2608];   // 64 b x 40 + monotone stagger
  const int tid = threadIdx.x;
  const int b0 = blockIdx.x * 64, j0 = blockIdx.y * 128;
  const int w = tid >> 6, l = tid & 63, m = l & 15, g = l >> 4;

  const int wj = tid >> 1, wkh = (tid & 1) * 16;
  const unsigned short* wsrc = Wbf + (size_t)(j0 + wj) * 1024 + wkh;
  const int kp = tid >> 4, bq = (tid & 15) * 4;  // k-pair, 4 b per thread
  const unsigned short* xsrc = X + (size_t)(2 * kp) * B + b0 + bq;

  f32x4 acc[2][4];
#pragma unroll
  for (int jt = 0; jt < 2; ++jt)
#pragma unroll
    for (int bt = 0; bt < 4; ++bt) acc[jt][bt] = (f32x4){0.f, 0.f, 0.f, 0.f};

  short8v wreg0, wreg1;
  short4v xa, xb;

  wreg0 = *(const short8v*)(wsrc);
  wreg1 = *(const short8v*)(wsrc + 8);
  xa = *(const short4v*)(xsrc);
  xb = *(const short4v*)(xsrc + B);

  {
    *(short8v*)&Wl[0][wj * 40 + wkh] = wreg0;
    *(short8v*)&Wl[0][wj * 40 + wkh + 8] = wreg1;
    unsigned* xl = (unsigned*)&Xl[0][0];
#pragma unroll
    for (int i = 0; i < 4; ++i) {
      const int b = bq + i;
      xl[b * 20 + (b >> 3) * 4 + kp] = (unsigned)(unsigned short)xa[i] |
                                       ((unsigned)(unsigned short)xb[i] << 16);
    }
  }
  __syncthreads();

  for (int t = 0; t < 32; ++t) {
    const int cur = t & 1;
    if (t < 31) {
      const unsigned short* wp = wsrc + (t + 1) * 32;
      wreg0 = *(const short8v*)(wp);
      wreg1 = *(const short8v*)(wp + 8);
      const unsigned short* xp = xsrc + (size_t)(t + 1) * 32 * B;
      xa = *(const short4v*)(xp);
      xb = *(const short4v*)(xp + B);
    }
    {
      short8v aw[2], bx[4];
#pragma unroll
      for (int jt = 0; jt < 2; ++jt)
        aw[jt] = *(const short8v*)&Wl[cur][(w * 32 + jt * 16 + m) * 40 + g * 8];
#pragma unroll
      for (int bt = 0; bt < 4; ++bt) {
        const int b = bt * 16 + m;
        bx[bt] = *(const short8v*)&Xl[cur][b * 40 + (b >> 3) * 8 + g * 8];
      }
#pragma unroll
      for (int jt = 0; jt < 2; ++jt)
#pragma unroll
        for (int bt = 0; bt < 4; ++bt)
          acc[jt][bt] = __builtin_amdgcn_mfma_f32_16x16x32_bf16(
              aw[jt], bx[bt], acc[jt][bt], 0, 0, 0);
    }
    if (t < 31) {
      const int nxt = cur ^ 1;
      *(short8v*)&Wl[nxt][wj * 40 + wkh] = wreg0;
      *(short8v*)&Wl[nxt][wj * 40 + wkh + 8] = wreg1;
      unsigned* xl = (unsigned*)&Xl[nxt][0];
#pragma unroll
      for (int i = 0; i < 4; ++i) {
        const int b = bq + i;
        xl[b * 20 + (b >> 3) * 4 + kp] =
            (unsigned)(unsigned short)xa[i] |
            ((unsigned)(unsigned short)xb[i] << 16);
      }
    }
    __syncthreads();
  }

#pragma unroll
  for (int jt = 0; jt < 2; ++jt)
#pragma unroll
    for (int r = 0; r < 4; ++r) {
      const int j = j0 + w * 32 + jt * 16 + g * 4 + r;
      const float bj = fb1[j];
#pragma unroll
      for (int bt = 0; bt < 4; ++bt)
        out[(size_t)j * B + b0 + bt * 16 + m] =
            f2bf(fmaxf(acc[jt][bt][r] + bj, 0.f));
    }
}

// ---------------- FC2: out[b,10] = fw2[10,512] @ h4[512,B] + fb2 -----------
__global__ __launch_bounds__(512) void k_fc2(
    const unsigned short* __restrict__ in, const float* __restrict__ fw2,
    const float* __restrict__ fb2, float* __restrict__ out, int B, int b0) {
  __shared__ float red[8][10][64];
  const int tx = threadIdx.x;
  const int b = blockIdx.x * 64 + tx;
  const int tyu = threadIdx.y;
  float acc[10];
#pragma unroll
  for (int i = 0; i < 10; ++i) acc[i] = 0.f;
  for (int kk = 0; kk < 64; ++kk) {
    const int k = tyu * 64 + kk;
    const float v = bf2f(in[(size_t)k * B + b]);
#pragma unroll
    for (int i = 0; i < 10; ++i) acc[i] = fmaf(v, fw2[i * 512 + k], acc[i]);
  }
#pragma unroll
  for (int i = 0; i < 10; ++i) red[tyu][i][tx] = acc[i];
  __syncthreads();
  if (tyu == 0) {
#pragma unroll
    for (int i = 0; i < 10; ++i) {
      float s = fb2[i];
#pragma unroll
      for (int q = 0; q < 8; ++q) s += red[q][i][tx];
      out[(size_t)(b0 + b) * 10 + i] = s;
    }
  }
}

extern "C" void kernel_launch(void* const* d_in, const int* in_sizes, int n_in,
                              void* d_out, int out_size, void* d_ws,
                              size_t ws_size, hipStream_t stream) {
  const float* x   = (const float*)d_in[0];
  const float* w1  = (const float*)d_in[1];
  const float* b1  = (const float*)d_in[2];
  const float* w2  = (const float*)d_in[3];
  const float* b2  = (const float*)d_in[4];
  const float* w3  = (const float*)d_in[5];
  const float* b3  = (const float*)d_in[6];
  const float* fw1 = (const float*)d_in[7];
  const float* fb1 = (const float*)d_in[8];
  const float* fw2 = (const float*)d_in[9];
  const float* fb2 = (const float*)d_in[10];
  float* out = (float*)d_out;

  const int B = in_sizes[0] / 784;  // 8192

  // ws (float units): Wm1[169*16*32 bf16] | Wm2 | Wm3 | Wbf | bf16 buffers
  const size_t nWm1 = (size_t)169 * 16 * 32 / 2;
  const size_t nWm2 = (size_t)36 * 32 * 160 / 2;
  const size_t nWm3 = (size_t)16 * 64 * 288 / 2;
  const size_t nWbf = (size_t)512 * 1024 / 2;
  unsigned short* Wm1 = (unsigned short*)d_ws;
  unsigned short* Wm2 = (unsigned short*)((float*)d_ws + nWm1);
  unsigned short* Wm3 = (unsigned short*)((float*)d_ws + nWm1 + nWm2);
  unsigned short* Wbf = (unsigned short*)((float*)d_ws + nWm1 + nWm2 + nWm3);
  unsigned short* hbase =
      (unsigned short*)((float*)d_ws + nWm1 + nWm2 + nWm3 + nWbf);
  const size_t ws_rem =
      ws_size - (nWm1 + nWm2 + nWm3 + nWbf) * sizeof(float);

  // per-batch-element bf16 shorts: xT 784 + h1 2704 + h2 1152 + h3 1024 + h4 512
  const size_t per_elem = (size_t)(784 + 2704 + 1152 + 1024 + 512) * 2;
  int Bc = B;
  while ((size_t)Bc * per_elem > ws_rem && Bc > 512) Bc >>= 1;
  const int nch = B / Bc;

  unsigned short* XT = hbase;
  unsigned short* H1 = XT + (size_t)784 * Bc;
  unsigned short* H2 = H1 + (size_t)2704 * Bc;
  unsigned short* H3 = H2 + (size_t)1152 * Bc;
  unsigned short* H4 = H3 + (size_t)1024 * Bc;

  // one-time weight transforms
  k_wmc<16, 1, 169, 32><<<dim3(169, 16), 32, 0, stream>>>(w1, Wm1);
  k_wmc<32, 16, 36, 160><<<dim3(36, 32), 160, 0, stream>>>(w2, Wm2);
  k_wmc<64, 32, 16, 288><<<dim3(16, 64), 288, 0, stream>>>(w3, Wm3);
  k_wbf<<<dim3(256), 256, 0, stream>>>(fw1, Wbf);

  for (int ch = 0; ch < nch; ++ch) {
    const float* xc = x + (size_t)ch * Bc * 784;
    const int b0 = ch * Bc;
    const int nbt = Bc / 128;

    // transpose + bf16: x[B,784] -> xT[784,Bc]
    k_trb<<<dim3(Bc / 32, 25), dim3(32, 8), 0, stream>>>(xc, XT, Bc);
    // LC1 per-position MFMA GEMM
    k_lcm<16, 9, 169, 784, 28, 13, 2, true>
        <<<dim3(nbt, 169), 256, 0, stream>>>(XT, Wm1, b1, H1, Bc);
    // LC2
    k_lcm<32, 144, 36, 169, 13, 6, 2, true>
        <<<dim3(nbt, 36), 256, 0, stream>>>(H1, Wm2, b2, H2, Bc);
    // LC3
    k_lcm<64, 288, 16, 36, 6, 4, 1, false>
        <<<dim3(nbt, 16), 256, 0, stream>>>(H2, Wm3, b3, H3, Bc);
    // FC1: h3 -> h4[512,Bc]  (64-b tiles: 512 blocks = 2/CU)
    k_fc1m<<<dim3(Bc / 64, 4), 256, 0, stream>>>(H3, Wbf, fb1, H4, Bc);
    // FC2: h4 -> out[b,10] f32  (8 waves/block)
    k_fc2<<<dim3(Bc / 64), dim3(64, 8), 0, stream>>>(H4, fw2, fb2, out, Bc,
                                                     b0);
  }
}

// Round 21
// 104.462 us; speedup vs baseline: 1.0918x; 1.0463x over previous
//
#include <hip/hip_runtime.h>

typedef __attribute__((ext_vector_type(8))) short short8v;   // 8 bf16
typedef __attribute__((ext_vector_type(4))) short short4v;   // 4 bf16
typedef __attribute__((ext_vector_type(4))) float f32x4;

static __device__ __forceinline__ unsigned short f2bf(float f) {
  union { float f; unsigned u; } v;
  v.f = f;
  const unsigned u = v.u;
  return (unsigned short)((u + 0x7FFF + ((u >> 16) & 1)) >> 16);  // RNE
}
static __device__ __forceinline__ float bf2f(unsigned short s) {
  union { unsigned u; float f; } v;
  v.u = ((unsigned)s) << 16;
  return v.f;
}

// Intermediates xT,h1..h4 stored bf16 in [feature, B] layout (batch-last).

// ---------------- transpose x[B,784] f32 -> xT[784, Bc] bf16 ---------------
__global__ __launch_bounds__(256) void k_trb(const float* __restrict__ x,
                                             unsigned short* __restrict__ xT,
                                             int Bc) {
  __shared__ float t[32][33];
  const int b0 = blockIdx.x * 32;
  const int f0 = blockIdx.y * 32;
  const int tx = threadIdx.x, ty = threadIdx.y;
  for (int r = ty; r < 32; r += 8) {
    const int f = f0 + tx;
    t[r][tx] = (f < 784) ? x[(size_t)(b0 + r) * 784 + f] : 0.f;
  }
  __syncthreads();
  for (int r = ty; r < 32; r += 8) {
    const int f = f0 + r;
    if (f < 784) xT[(size_t)f * Bc + b0 + tx] = f2bf(t[tx][r]);
  }
}

// ------ ALL weight transforms fused into one grid-stride kernel ------------
// Region layout (bf16 shorts):
//  [0, N1)              Wm1[pos][o][32]  (w1: O=16,C=1, NPOS=169, K=9)
//  [N1, N1+N2)          Wm2[pos][o][160] (w2: O=32,C=16,NPOS=36, K=144)
//  [N1+N2, N1+N2+N3)    Wm3[pos][o][288] (w3: O=64,C=32,NPOS=16, K=288)
//  [.., +N4)            Wbf[j*1024+k]    (fw1 bf16 copy)
__global__ __launch_bounds__(256) void k_wall(
    const float* __restrict__ w1, const float* __restrict__ w2,
    const float* __restrict__ w3, const float* __restrict__ fw1,
    unsigned short* __restrict__ Wm1, unsigned short* __restrict__ Wm2,
    unsigned short* __restrict__ Wm3, unsigned short* __restrict__ Wbf) {
  const int N1 = 169 * 16 * 32;      // 86528
  const int N2 = 36 * 32 * 160;      // 184320
  const int N3 = 16 * 64 * 288;      // 294912
  const int N4 = 512 * 1024;         // 524288
  const int total = N1 + N2 + N3 + N4;
  for (int i = blockIdx.x * 256 + threadIdx.x; i * 8 < total;
       i += gridDim.x * 256) {
    const int base = i * 8;
#pragma unroll
    for (int u = 0; u < 8; ++u) {
      const int idx = base + u;
      if (idx < N1) {
        const int pos = idx >> 9, rem = idx & 511;
        const int o = rem >> 5, k = rem & 31;
        const float v = (k < 9) ? w1[((size_t)o * 169 + pos) * 9 + k] : 0.f;
        Wm1[idx] = f2bf(v);
      } else if (idx < N1 + N2) {
        const int j = idx - N1;
        const int pos = j / (32 * 160), rem = j - pos * (32 * 160);
        const int o = rem / 160, k = rem - o * 160;
        float v = 0.f;
        if (k < 144) {
          const int c = k / 9, kk = k - c * 9;
          v = w2[((size_t)(o * 16 + c) * 36 + pos) * 9 + kk];
        }
        Wm2[j] = f2bf(v);
      } else if (idx < N1 + N2 + N3) {
        const int j = idx - N1 - N2;
        const int pos = j / (64 * 288), rem = j - pos * (64 * 288);
        const int o = rem / 288, k = rem - o * 288;
        const int c = k / 9, kk = k - c * 9;  // k < 288 always
        Wm3[j] = f2bf(w3[((size_t)(o * 32 + c) * 16 + pos) * 9 + kk]);
      } else {
        const int j = idx - N1 - N2 - N3;
        Wbf[j] = f2bf(fw1[j]);
      }
    }
  }
}

// ---------------- LC layer via bf16 MFMA (bf16 in, bf16 out) ---------------
// SINGLE-buffered LDS: all three LC layers hit the 8-blocks/CU TLP cap.
// Register prefetch of the next K-step's rows hides global latency across the
// two per-step barriers; cross-block TLP covers the rest (m114).
// Wave split: O=64: 32o x 64b (2jt x 4bt); O=32: 32o x 32b; O=16: 16o x 32b.
template <int O, int K, int NPOS, int HWIN, int WIN, int WOD, int STR,
          bool RELU>
__global__ __launch_bounds__(256) void k_lcm(
    const unsigned short* __restrict__ X, const unsigned short* __restrict__ Wm,
    const float* __restrict__ bias, unsigned short* __restrict__ out, int B) {
  constexpr int NSTEP = (K + 31) / 32;
  constexpr int Kpad = NSTEP * 32;
  constexpr int NJT = (O >= 32) ? 2 : 1;                      // o-tiles/wave
  constexpr int NBT = (O == 64) ? 4 : 2;                      // b-tiles/wave
  __shared__ short Wl[O * 40];
  __shared__ short Xl[5232];
  __shared__ int rowtab[Kpad];
  const int tid = threadIdx.x;
  const int b0 = blockIdx.x * 128;
  const int pos = blockIdx.y;
  const int ho = pos / WOD, wo = pos - ho * WOD;
  const int w = tid >> 6, l = tid & 63, m = l & 15, g = l >> 4;
  const int jw = (O == 64) ? (w & 1) * 32 : 0;                // o origin
  const int boff = (O == 64) ? (w >> 1) * 64
                             : ((O == 32) ? w * 32 : (w & 3) * 32);

  for (int k = tid; k < Kpad; k += 256) {
    int r = 0;
    if (k < K) {
      const int c = k / 9, kk = k - c * 9;
      const int kh = kk / 3, kw = kk - kh * 3;
      r = c * HWIN + (ho * STR + kh) * WIN + (wo * STR + kw);
    }
    rowtab[k] = r;
  }
  __syncthreads();

  const unsigned short* wsrc = Wm + (size_t)pos * O * Kpad;
  const int wjj = tid >> 2, wko = (tid & 3) * 8;
  const bool wact = tid < O * 4;
  const int kp = tid >> 4, boct = (tid & 15) * 8;

  f32x4 acc[NJT][NBT];
#pragma unroll
  for (int jt = 0; jt < NJT; ++jt)
#pragma unroll
    for (int bt = 0; bt < NBT; ++bt) acc[jt][bt] = (f32x4){0.f, 0.f, 0.f, 0.f};

  short8v wreg, xa, xb;
  bool z0, z1;

  // ---- prologue: load + stage step 0
  if (wact) wreg = *(const short8v*)&wsrc[(size_t)wjj * Kpad + wko];
  {
    const int k0 = 2 * kp;
    z0 = k0 >= K;
    z1 = k0 + 1 >= K;
    if (!z0) xa = *(const short8v*)(X + (size_t)rowtab[k0] * B + b0 + boct);
    if (!z1)
      xb = *(const short8v*)(X + (size_t)rowtab[k0 + 1] * B + b0 + boct);
  }
  if (wact) *(short8v*)&Wl[wjj * 40 + wko] = wreg;
  {
    unsigned* xl = (unsigned*)&Xl[0];
#pragma unroll
    for (int i = 0; i < 8; ++i) {
      const int b = boct + i;
      const unsigned lo = z0 ? 0u : (unsigned)(unsigned short)xa[i];
      const unsigned hi = z1 ? 0u : (unsigned)(unsigned short)xb[i];
      xl[b * 20 + (b >> 3) * 4 + kp] = lo | (hi << 16);
    }
  }
  __syncthreads();

  for (int t = 0; t < NSTEP; ++t) {
    if (t < NSTEP - 1) {  // issue next step's loads into registers
      const int kc = (t + 1) * 32;
      if (wact) wreg = *(const short8v*)&wsrc[(size_t)wjj * Kpad + kc + wko];
      const int k0 = kc + 2 * kp;
      z0 = k0 >= K;
      z1 = k0 + 1 >= K;
      if (!z0) xa = *(const short8v*)(X + (size_t)rowtab[k0] * B + b0 + boct);
      if (!z1)
        xb = *(const short8v*)(X + (size_t)rowtab[k0 + 1] * B + b0 + boct);
    }
    {
      short8v aw[NJT], bx[NBT];
#pragma unroll
      for (int jt = 0; jt < NJT; ++jt)
        aw[jt] = *(const short8v*)&Wl[(jw + jt * 16 + m) * 40 + g * 8];
#pragma unroll
      for (int bt = 0; bt < NBT; ++bt) {
        const int b = boff + bt * 16 + m;
        bx[bt] = *(const short8v*)&Xl[b * 40 + (b >> 3) * 8 + g * 8];
      }
#pragma unroll
      for (int jt = 0; jt < NJT; ++jt)
#pragma unroll
        for (int bt = 0; bt < NBT; ++bt)
          acc[jt][bt] = __builtin_amdgcn_mfma_f32_16x16x32_bf16(
              aw[jt], bx[bt], acc[jt][bt], 0, 0, 0);
    }
    if (t < NSTEP - 1) {
      __syncthreads();  // all waves done reading Xl/Wl
      if (wact) *(short8v*)&Wl[wjj * 40 + wko] = wreg;
      unsigned* xl = (unsigned*)&Xl[0];
#pragma unroll
      for (int i = 0; i < 8; ++i) {
        const int b = boct + i;
        const unsigned lo = z0 ? 0u : (unsigned)(unsigned short)xa[i];
        const unsigned hi = z1 ? 0u : (unsigned)(unsigned short)xb[i];
        xl[b * 20 + (b >> 3) * 4 + kp] = lo | (hi << 16);
      }
      __syncthreads();  // writes visible before next MFMA
    }
  }

#pragma unroll
  for (int jt = 0; jt < NJT; ++jt)
#pragma unroll
    for (int r = 0; r < 4; ++r) {
      const int o = jw + jt * 16 + g * 4 + r;
      const int f = o * NPOS + pos;
      const float bz = bias[f];
#pragma unroll
      for (int bt = 0; bt < NBT; ++bt) {
        float v = acc[jt][bt][r] + bz;
        if (RELU) v = fmaxf(v, 0.f);
        out[(size_t)f * B + b0 + boff + bt * 16 + m] = f2bf(v);
      }
    }
}

// ---------------- FC1 via bf16 MFMA, 64-b tiles (2 blocks/CU) --------------
__global__ __launch_bounds__(256) void k_fc1m(
    const unsigned short* __restrict__ X,
    const unsigned short* __restrict__ Wbf, const float* __restrict__ fb1,
    unsigned short* __restrict__ out, int B) {
  __shared__ short Wl[2][5120];   // 128 j x 40 shorts
  __shared__ short Xl[2][2608];   // 64 b x 40 + monotone stagger
  const int tid = threadIdx.x;
  const int b0 = blockIdx.x * 64, j0 = blockIdx.y * 128;
  const int w = tid >> 6, l = tid & 63, m = l & 15, g = l >> 4;

  const int wj = tid >> 1, wkh = (tid & 1) * 16;
  const unsigned short* wsrc = Wbf + (size_t)(j0 + wj) * 1024 + wkh;
  const int kp = tid >> 4, bq = (tid & 15) * 4;  // k-pair, 4 b per thread
  const unsigned short* xsrc = X + (size_t)(2 * kp) * B + b0 + bq;

  f32x4 acc[2][4];
#pragma unroll
  for (int jt = 0; jt < 2; ++jt)
#pragma unroll
    for (int bt = 0; bt < 4; ++bt) acc[jt][bt] = (f32x4){0.f, 0.f, 0.f, 0.f};

  short8v wreg0, wreg1;
  short4v xa, xb;

  wreg0 = *(const short8v*)(wsrc);
  wreg1 = *(const short8v*)(wsrc + 8);
  xa = *(const short4v*)(xsrc);
  xb = *(const short4v*)(xsrc + B);

  {
    *(short8v*)&Wl[0][wj * 40 + wkh] = wreg0;
    *(short8v*)&Wl[0][wj * 40 + wkh + 8] = wreg1;
    unsigned* xl = (unsigned*)&Xl[0][0];
#pragma unroll
    for (int i = 0; i < 4; ++i) {
      const int b = bq + i;
      xl[b * 20 + (b >> 3) * 4 + kp] = (unsigned)(unsigned short)xa[i] |
                                       ((unsigned)(unsigned short)xb[i] << 16);
    }
  }
  __syncthreads();

  for (int t = 0; t < 32; ++t) {
    const int cur = t & 1;
    if (t < 31) {
      const unsigned short* wp = wsrc + (t + 1) * 32;
      wreg0 = *(const short8v*)(wp);
      wreg1 = *(const short8v*)(wp + 8);
      const unsigned short* xp = xsrc + (size_t)(t + 1) * 32 * B;
      xa = *(const short4v*)(xp);
      xb = *(const short4v*)(xp + B);
    }
    {
      short8v aw[2], bx[4];
#pragma unroll
      for (int jt = 0; jt < 2; ++jt)
        aw[jt] = *(const short8v*)&Wl[cur][(w * 32 + jt * 16 + m) * 40 + g * 8];
#pragma unroll
      for (int bt = 0; bt < 4; ++bt) {
        const int b = bt * 16 + m;
        bx[bt] = *(const short8v*)&Xl[cur][b * 40 + (b >> 3) * 8 + g * 8];
      }
#pragma unroll
      for (int jt = 0; jt < 2; ++jt)
#pragma unroll
        for (int bt = 0; bt < 4; ++bt)
          acc[jt][bt] = __builtin_amdgcn_mfma_f32_16x16x32_bf16(
              aw[jt], bx[bt], acc[jt][bt], 0, 0, 0);
    }
    if (t < 31) {
      const int nxt = cur ^ 1;
      *(short8v*)&Wl[nxt][wj * 40 + wkh] = wreg0;
      *(short8v*)&Wl[nxt][wj * 40 + wkh + 8] = wreg1;
      unsigned* xl = (unsigned*)&Xl[nxt][0];
#pragma unroll
      for (int i = 0; i < 4; ++i) {
        const int b = bq + i;
        xl[b * 20 + (b >> 3) * 4 + kp] =
            (unsigned)(unsigned short)xa[i] |
            ((unsigned)(unsigned short)xb[i] << 16);
      }
    }
    __syncthreads();
  }

#pragma unroll
  for (int jt = 0; jt < 2; ++jt)
#pragma unroll
    for (int r = 0; r < 4; ++r) {
      const int j = j0 + w * 32 + jt * 16 + g * 4 + r;
      const float bj = fb1[j];
#pragma unroll
      for (int bt = 0; bt < 4; ++bt)
        out[(size_t)j * B + b0 + bt * 16 + m] =
            f2bf(fmaxf(acc[jt][bt][r] + bj, 0.f));
    }
}

// ---------------- FC2: out[b,10] = fw2[10,512] @ h4[512,B] + fb2 -----------
__global__ __launch_bounds__(512) void k_fc2(
    const unsigned short* __restrict__ in, const float* __restrict__ fw2,
    const float* __restrict__ fb2, float* __restrict__ out, int B, int b0) {
  __shared__ float red[8][10][64];
  const int tx = threadIdx.x;
  const int b = blockIdx.x * 64 + tx;
  const int tyu = threadIdx.y;
  float acc[10];
#pragma unroll
  for (int i = 0; i < 10; ++i) acc[i] = 0.f;
  for (int kk = 0; kk < 64; ++kk) {
    const int k = tyu * 64 + kk;
    const float v = bf2f(in[(size_t)k * B + b]);
#pragma unroll
    for (int i = 0; i < 10; ++i) acc[i] = fmaf(v, fw2[i * 512 + k], acc[i]);
  }
#pragma unroll
  for (int i = 0; i < 10; ++i) red[tyu][i][tx] = acc[i];
  __syncthreads();
  if (tyu == 0) {
#pragma unroll
    for (int i = 0; i < 10; ++i) {
      float s = fb2[i];
#pragma unroll
      for (int q = 0; q < 8; ++q) s += red[q][i][tx];
      out[(size_t)(b0 + b) * 10 + i] = s;
    }
  }
}

extern "C" void kernel_launch(void* const* d_in, const int* in_sizes, int n_in,
                              void* d_out, int out_size, void* d_ws,
                              size_t ws_size, hipStream_t stream) {
  const float* x   = (const float*)d_in[0];
  const float* w1  = (const float*)d_in[1];
  const float* b1  = (const float*)d_in[2];
  const float* w2  = (const float*)d_in[3];
  const float* b2  = (const float*)d_in[4];
  const float* w3  = (const float*)d_in[5];
  const float* b3  = (const float*)d_in[6];
  const float* fw1 = (const float*)d_in[7];
  const float* fb1 = (const float*)d_in[8];
  const float* fw2 = (const float*)d_in[9];
  const float* fb2 = (const float*)d_in[10];
  float* out = (float*)d_out;

  const int B = in_sizes[0] / 784;  // 8192

  // ws (float units): Wm1[169*16*32 bf16] | Wm2 | Wm3 | Wbf | bf16 buffers
  const size_t nWm1 = (size_t)169 * 16 * 32 / 2;
  const size_t nWm2 = (size_t)36 * 32 * 160 / 2;
  const size_t nWm3 = (size_t)16 * 64 * 288 / 2;
  const size_t nWbf = (size_t)512 * 1024 / 2;
  unsigned short* Wm1 = (unsigned short*)d_ws;
  unsigned short* Wm2 = (unsigned short*)((float*)d_ws + nWm1);
  unsigned short* Wm3 = (unsigned short*)((float*)d_ws + nWm1 + nWm2);
  unsigned short* Wbf = (unsigned short*)((float*)d_ws + nWm1 + nWm2 + nWm3);
  unsigned short* hbase =
      (unsigned short*)((float*)d_ws + nWm1 + nWm2 + nWm3 + nWbf);
  const size_t ws_rem =
      ws_size - (nWm1 + nWm2 + nWm3 + nWbf) * sizeof(float);

  // per-batch-element bf16 shorts: xT 784 + h1 2704 + h2 1152 + h3 1024 + h4 512
  const size_t per_elem = (size_t)(784 + 2704 + 1152 + 1024 + 512) * 2;
  int Bc = B;
  while ((size_t)Bc * per_elem > ws_rem && Bc > 512) Bc >>= 1;
  const int nch = B / Bc;

  unsigned short* XT = hbase;
  unsigned short* H1 = XT + (size_t)784 * Bc;
  unsigned short* H2 = H1 + (size_t)2704 * Bc;
  unsigned short* H3 = H2 + (size_t)1152 * Bc;
  unsigned short* H4 = H3 + (size_t)1024 * Bc;

  // one-time weight transforms: single fused launch (was 4 serial launches)
  k_wall<<<dim3(533), 256, 0, stream>>>(w1, w2, w3, fw1, Wm1, Wm2, Wm3, Wbf);

  for (int ch = 0; ch < nch; ++ch) {
    const float* xc = x + (size_t)ch * Bc * 784;
    const int b0 = ch * Bc;
    const int nbt = Bc / 128;

    // transpose + bf16: x[B,784] -> xT[784,Bc]
    k_trb<<<dim3(Bc / 32, 25), dim3(32, 8), 0, stream>>>(xc, XT, Bc);
    // LC1 per-position MFMA GEMM
    k_lcm<16, 9, 169, 784, 28, 13, 2, true>
        <<<dim3(nbt, 169), 256, 0, stream>>>(XT, Wm1, b1, H1, Bc);
    // LC2
    k_lcm<32, 144, 36, 169, 13, 6, 2, true>
        <<<dim3(nbt, 36), 256, 0, stream>>>(H1, Wm2, b2, H2, Bc);
    // LC3
    k_lcm<64, 288, 16, 36, 6, 4, 1, false>
        <<<dim3(nbt, 16), 256, 0, stream>>>(H2, Wm3, b3, H3, Bc);
    // FC1: h3 -> h4[512,Bc]  (64-b tiles: 512 blocks = 2/CU)
    k_fc1m<<<dim3(Bc / 64, 4), 256, 0, stream>>>(H3, Wbf, fb1, H4, Bc);
    // FC2: h4 -> out[b,10] f32  (8 waves/block)
    k_fc2<<<dim3(Bc / 64), dim3(64, 8), 0, stream>>>(H4, fw2, fb2, out, Bc,
                                                     b0);
  }
}